// Round 14
// baseline (29.497 us; speedup 1.0000x reference)
//
#include <hip/hip_runtime.h>
#include <stdint.h>

#define NB 4096
#define QLEN 1024
#define NL 64
#define KLEN 32
#define NS (QLEN - KLEN + 1)   // 993
#define SLICE 1840             // u32 per row slice (pkE 528 | pkO 528 | nwh 512 | s4 264f)

typedef __attribute__((ext_vector_type(8))) _Float16 half8;
typedef __attribute__((ext_vector_type(4))) float f32x4;

union fragh { uint32_t u[4]; half8 v; };

static __device__ __forceinline__ uint32_t pkh(float a, float b) {
    return __builtin_bit_cast(uint32_t, __builtin_amdgcn_cvt_pkrtz(a, b)); // v_cvt_pkrtz_f16_f32
}
static __device__ __forceinline__ float lo16f(uint32_t w) {
    return (float)__builtin_bit_cast(_Float16, (unsigned short)(w & 0xFFFFu));
}
static __device__ __forceinline__ float hi16f(uint32_t w) {
    return (float)__builtin_bit_cast(_Float16, (unsigned short)(w >> 16));
}
static __device__ __forceinline__ uint32_t pkh_rne(float a, float b) {  // RNE f16 pair
    unsigned short ha = __builtin_bit_cast(unsigned short, (_Float16)a);
    unsigned short hb = __builtin_bit_cast(unsigned short, (_Float16)b);
    return (uint32_t)ha | ((uint32_t)hb << 16);
}

// Kernel 1: block = 4 waves = 2 rows; each row's 2 waves split the FEATURE dim.
// No __syncthreads anywhere: both waves of a row redundantly pack the shared
// slice (identical values -> benign collisions); wave_barrier orders own RAW.
__global__ __launch_bounds__(256, 8) void shapelet_r14(
    const float* __restrict__ ts,        // [B, Q]
    const float* __restrict__ shapelets, // [L, K]
    const float* __restrict__ fc_w,      // [2, L]
    float* __restrict__ ws)              // [B, 4] half-partials
{
    __shared__ __align__(16) uint32_t lds[2 * SLICE];   // 14.7 KB -> 8 blocks/CU

    const int tid  = threadIdx.x;
    const int lane = tid & 63;
    const int wave = tid >> 6;
    const int rw   = wave >> 1;          // row-in-block (0,1)
    const int h    = wave & 1;           // feature half (l-tiles 2h, 2h+1)
    const int col  = lane & 15;
    const int kg   = lane >> 4;
    const int row  = blockIdx.x * 2 + rw;

    uint32_t* pkE = lds + rw * SLICE;                      // [528]
    uint32_t* pkO = pkE + 528;                             // [528]
    uint32_t* nwh = pkO + 528;                             // [512]
    float*    s4  = reinterpret_cast<float*>(nwh + 512);   // [264]

    // --- pass 1: FULL row pack (duplicated by both waves of the row) ---
    const float* rowp = ts + (size_t)row * QLEN;
    #pragma unroll
    for (int c = 0; c < 4; ++c) {
        float4 v = reinterpret_cast<const float4*>(rowp)[64 * c + lane];
        const int p = 256 * c + 4 * lane + 4;
        float x4 = (p < QLEN) ? rowp[p] : 0.0f;
        uint2 pe = { pkh(v.x, v.y), pkh(v.z, v.w) };
        uint2 po = { pkh(v.y, v.z), pkh(v.w, x4) };
        reinterpret_cast<uint2*>(pkE)[64 * c + lane] = pe;
        reinterpret_cast<uint2*>(pkO)[64 * c + lane] = po;
        s4[64 * c + lane] =
            fmaf(v.x, v.x, fmaf(v.y, v.y, fmaf(v.z, v.z, v.w * v.w)));
    }
    if (lane < 16) { pkE[512 + lane] = 0u; pkO[512 + lane] = 0u; }
    if (lane < 8)  s4[256 + lane] = 0.0f;

    // --- B fragments for OWN 2 l-tiles (8 VGPR) + exact fp32 ssq partials ---
    fragh Bh[2];
    float ssq[2];
    #pragma unroll
    for (int t = 0; t < 2; ++t) {
        const int lt = 2 * h + t;
        const float* sp = shapelets + (lt * 16 + col) * KLEN + kg * 8;
        float4 f0 = *reinterpret_cast<const float4*>(sp);
        float4 f1 = *reinterpret_cast<const float4*>(sp + 4);
        Bh[t].u[0] = pkh(f0.x, f0.y);
        Bh[t].u[1] = pkh(f0.z, f0.w);
        Bh[t].u[2] = pkh(f1.x, f1.y);
        Bh[t].u[3] = pkh(f1.z, f1.w);
        float s = f0.x * f0.x;
        s = fmaf(f0.y, f0.y, s); s = fmaf(f0.z, f0.z, s); s = fmaf(f0.w, f0.w, s);
        s = fmaf(f1.x, f1.x, s); s = fmaf(f1.y, f1.y, s);
        s = fmaf(f1.z, f1.z, s); s = fmaf(f1.w, f1.w, s);
        ssq[t] = s;   // kg-partial; reduced in epilogue
    }

    __builtin_amdgcn_wave_barrier();   // own pass-1 writes before own pass-2 reads

    // --- pass 2: full nwh (duplicated, identical); f16 readbacks for corrections ---
    #pragma unroll
    for (int c = 0; c < 4; ++c) {
        const int q = 64 * c + lane;
        float s_[8];
        #pragma unroll
        for (int j = 0; j < 8; ++j) s_[j] = s4[q + j];
        float w0 = ((s_[0] + s_[1]) + (s_[2] + s_[3])) + ((s_[4] + s_[5]) + (s_[6] + s_[7]));
        uint32_t a0  = pkE[2 * q];
        uint32_t a1  = pkE[2 * q + 1];
        uint32_t cw0 = pkE[2 * (q + 8)];
        uint32_t cw1 = pkE[2 * (q + 8) + 1];
        float x0  = lo16f(a0),  x1  = hi16f(a0),  x2  = lo16f(a1);
        float x32 = lo16f(cw0), x33 = hi16f(cw0), x34 = lo16f(cw1);
        float w1 = fmaf(x32, x32, fmaf(-x0, x0, w0));
        float w2 = fmaf(x33, x33, fmaf(-x1, x1, w1));
        float w3 = fmaf(x34, x34, fmaf(-x2, x2, w2));
        const int p0 = 4 * q;
        float c0 = (p0 + 0 < NS) ? -0.5f * w0 : -60000.0f;
        float c1 = (p0 + 1 < NS) ? -0.5f * w1 : -60000.0f;
        float c2 = (p0 + 2 < NS) ? -0.5f * w2 : -60000.0f;
        float c3 = (p0 + 3 < NS) ? -0.5f * w3 : -60000.0f;
        const int qq = p0 & 31;
        const int W = ((p0 >> 5) << 4) + (((qq & 15) >> 2) << 2) + ((qq >> 4) << 1);
        uint2 hw = { pkh_rne(c0, c1), pkh_rne(c2, c3) };
        *reinterpret_cast<uint2*>(&nwh[W]) = hw;
    }

    __builtin_amdgcn_wave_barrier();   // own pass-2 stores before main-loop reads

    // --- main loop: 32 tile-pairs (full row), 2 l-tiles, r12's body halved ---
    float rmax[2][4];
    #pragma unroll
    for (int t = 0; t < 2; ++t)
        #pragma unroll
        for (int e = 0; e < 4; ++e) rmax[t][e] = -3.0e38f;

    const int par = col & 1;
    const uint32_t* apk = (par ? pkO : pkE) + (((col - par) >> 1) + kg * 4);
    const int nwb = 4 * kg;

    #pragma unroll 2
    for (int i = 0; i < 32; ++i) {
        const uint32_t* ap = apk + 16 * i;
        fragh Aa, Ab;
        #pragma unroll
        for (int j = 0; j < 4; ++j) Aa.u[j] = ap[j];
        #pragma unroll
        for (int j = 0; j < 4; ++j) Ab.u[j] = ap[8 + j];

        uint4 nw = *reinterpret_cast<const uint4*>(&nwh[16 * i + nwb]);
        f32x4 ia, ib;
        ia[0] = lo16f(nw.x); ia[1] = hi16f(nw.x);
        ia[2] = lo16f(nw.y); ia[3] = hi16f(nw.y);
        ib[0] = lo16f(nw.z); ib[1] = hi16f(nw.z);
        ib[2] = lo16f(nw.w); ib[3] = hi16f(nw.w);

        #pragma unroll
        for (int t = 0; t < 2; ++t) {
            f32x4 aa = __builtin_amdgcn_mfma_f32_16x16x32_f16(Aa.v, Bh[t].v, ia, 0, 0, 0);
            f32x4 ab = __builtin_amdgcn_mfma_f32_16x16x32_f16(Ab.v, Bh[t].v, ib, 0, 0, 0);
            #pragma unroll
            for (int e = 0; e < 4; ++e)
                rmax[t][e] = fmaxf(fmaxf(aa[e], ab[e]), rmax[t][e]);  // v_max3_f32
        }
    }

    // --- epilogue: in-wave shuffles only; store half-partials to ws ---
    float p0v = 0.0f, p1v = 0.0f;
    #pragma unroll
    for (int t = 0; t < 2; ++t) {
        const int ft = (2 * h + t) * 16 + col;
        float m = fmaxf(fmaxf(rmax[t][0], rmax[t][1]),
                        fmaxf(rmax[t][2], rmax[t][3]));
        m = fmaxf(m, __shfl_xor(m, 16, 64));
        m = fmaxf(m, __shfl_xor(m, 32, 64));
        float sq = ssq[t];
        sq += __shfl_xor(sq, 16, 64);
        sq += __shfl_xor(sq, 32, 64);
        float f = (sq - 2.0f * m) * (1.0f / (float)KLEN);   // min dist
        p0v = fmaf(f, fc_w[ft], p0v);
        p1v = fmaf(f, fc_w[NL + ft], p1v);
    }
    #pragma unroll
    for (int off = 1; off <= 8; off <<= 1) {
        p0v += __shfl_xor(p0v, off, 64);
        p1v += __shfl_xor(p1v, off, 64);
    }
    if (lane == 0) {
        ws[(size_t)row * 4 + 2 * h + 0] = p0v;
        ws[(size_t)row * 4 + 2 * h + 1] = p1v;
    }
}

// Kernel 2: deterministic merge of the two feature-half partials + bias.
__global__ __launch_bounds__(256) void shapelet_fin(
    const float* __restrict__ ws, const float* __restrict__ fc_b,
    float* __restrict__ out)
{
    const int idx = blockIdx.x * 256 + threadIdx.x;   // 0 .. 2*NB-1
    if (idx < 2 * NB) {
        const int row = idx >> 1, c = idx & 1;
        out[idx] = ws[4 * row + c] + ws[4 * row + 2 + c] + fc_b[c];
    }
}

extern "C" void kernel_launch(void* const* d_in, const int* in_sizes, int n_in,
                              void* d_out, int out_size, void* d_ws, size_t ws_size,
                              hipStream_t stream) {
    const float* ts        = (const float*)d_in[0];
    const float* shapelets = (const float*)d_in[1];
    const float* fc_w      = (const float*)d_in[2];
    const float* fc_b      = (const float*)d_in[3];
    float* out = (float*)d_out;
    float* ws  = (float*)d_ws;

    shapelet_r14<<<NB / 2, 256, 0, stream>>>(ts, shapelets, fc_w, ws);
    shapelet_fin<<<(2 * NB + 255) / 256, 256, 0, stream>>>(ws, fc_b, out);
}

// Round 15
// 23.450 us; speedup vs baseline: 1.2579x; 1.2579x over previous
//
#include <hip/hip_runtime.h>
#include <stdint.h>

#define NB 4096
#define QLEN 1024
#define NL 64
#define KLEN 32
#define NS (QLEN - KLEN + 1)   // 993
#define WSLICE 1856            // u32 per wave LDS slice

typedef __attribute__((ext_vector_type(8))) _Float16 half8;
typedef __attribute__((ext_vector_type(4))) float f32x4;

union fragh { uint32_t u[4]; half8 v; };

static __device__ __forceinline__ uint32_t pkh(float a, float b) {
    return __builtin_bit_cast(uint32_t, __builtin_amdgcn_cvt_pkrtz(a, b)); // v_cvt_pkrtz_f16_f32
}
static __device__ __forceinline__ float lo16f(uint32_t w) {
    return (float)__builtin_bit_cast(_Float16, (unsigned short)(w & 0xFFFFu));
}
static __device__ __forceinline__ float hi16f(uint32_t w) {
    return (float)__builtin_bit_cast(_Float16, (unsigned short)(w >> 16));
}
static __device__ __forceinline__ uint32_t pkh_rne(float a, float b) {  // RNE f16 pair
    unsigned short ha = __builtin_bit_cast(unsigned short, (_Float16)a);
    unsigned short hb = __builtin_bit_cast(unsigned short, (_Float16)b);
    return (uint32_t)ha | ((uint32_t)hb << 16);
}

__global__ __launch_bounds__(256, 4) void shapelet_r15(
    const float* __restrict__ ts,        // [B, Q]
    const float* __restrict__ shapelets, // [L, K]
    const float* __restrict__ fc_w,      // [2, L]
    const float* __restrict__ fc_b,      // [2]
    float* __restrict__ out)             // [B, 2]
{
    // 4 private slices, one per wave; NO __syncthreads in this kernel.
    __shared__ __align__(16) uint32_t lds[4 * WSLICE];   // 29.7 KB

    const int tid  = threadIdx.x;
    const int wave = tid >> 6;
    const int lane = tid & 63;
    const int col  = lane & 15;
    const int kg   = lane >> 4;
    const int row  = blockIdx.x * 4 + wave;   // this wave's batch row

    uint32_t* pkE = lds + wave * WSLICE;                   // [528]
    uint32_t* pkO = pkE + 528;                             // [528]
    uint32_t* nwh = pkO + 528;                             // [512]
    float*    s4  = reinterpret_cast<float*>(nwh + 512);   // [264]

    // --- pass 1: wave loads its whole row (4 float4/lane), packs, partials ---
    const float* rowp = ts + (size_t)row * QLEN;
    float4 v[4];
    #pragma unroll
    for (int c = 0; c < 4; ++c)
        v[c] = reinterpret_cast<const float4*>(rowp)[64 * c + lane];
    float x4[4];
    #pragma unroll
    for (int c = 0; c < 4; ++c) {
        const int p = 256 * c + 4 * lane + 4;
        x4[c] = (p < QLEN) ? rowp[p] : 0.0f;
    }
    #pragma unroll
    for (int c = 0; c < 4; ++c) {
        uint2 pe = { pkh(v[c].x, v[c].y), pkh(v[c].z, v[c].w) };
        uint2 po = { pkh(v[c].y, v[c].z), pkh(v[c].w, x4[c]) };
        reinterpret_cast<uint2*>(pkE)[64 * c + lane] = pe;
        reinterpret_cast<uint2*>(pkO)[64 * c + lane] = po;
        s4[64 * c + lane] =
            fmaf(v[c].x, v[c].x, fmaf(v[c].y, v[c].y, fmaf(v[c].z, v[c].z, v[c].w * v[c].w)));
    }
    if (lane < 16) { pkE[512 + lane] = 0u; pkO[512 + lane] = 0u; }
    if (lane < 8)  s4[256 + lane] = 0.0f;

    // --- B fragments (fp16 RTZ) + exact fp32 ssq partials ---
    fragh Bh[4];
    float ssq[4];
    #pragma unroll
    for (int lt = 0; lt < 4; ++lt) {
        const float* sp = shapelets + (lt * 16 + col) * KLEN + kg * 8;
        float4 f0 = *reinterpret_cast<const float4*>(sp);
        float4 f1 = *reinterpret_cast<const float4*>(sp + 4);
        Bh[lt].u[0] = pkh(f0.x, f0.y);
        Bh[lt].u[1] = pkh(f0.z, f0.w);
        Bh[lt].u[2] = pkh(f1.x, f1.y);
        Bh[lt].u[3] = pkh(f1.z, f1.w);
        float s = f0.x * f0.x;
        s = fmaf(f0.y, f0.y, s); s = fmaf(f0.z, f0.z, s); s = fmaf(f0.w, f0.w, s);
        s = fmaf(f1.x, f1.x, s); s = fmaf(f1.y, f1.y, s);
        s = fmaf(f1.z, f1.z, s); s = fmaf(f1.w, f1.w, s);
        ssq[lt] = s;   // kg-partial; reduced in epilogue
    }

    __builtin_amdgcn_wave_barrier();   // order pass-1 LDS writes before pass-2 reads

    // --- pass 2: win_sq from s4 partials + f16 sliding corrections -> nwh ---
    #pragma unroll
    for (int c = 0; c < 4; ++c) {
        const int q = 64 * c + lane;
        float s_[8];
        #pragma unroll
        for (int j = 0; j < 8; ++j) s_[j] = s4[q + j];
        float w0 = ((s_[0] + s_[1]) + (s_[2] + s_[3])) + ((s_[4] + s_[5]) + (s_[6] + s_[7]));
        uint32_t cw0 = pkE[2 * (q + 8)];
        uint32_t cw1 = pkE[2 * (q + 8) + 1];
        float x32 = lo16f(cw0), x33 = hi16f(cw0), x34 = lo16f(cw1);
        float w1 = fmaf(x32, x32, fmaf(-v[c].x, v[c].x, w0));
        float w2 = fmaf(x33, x33, fmaf(-v[c].y, v[c].y, w1));
        float w3 = fmaf(x34, x34, fmaf(-v[c].z, v[c].z, w2));
        const int p0 = 4 * q;
        float c0 = (p0 + 0 < NS) ? -0.5f * w0 : -60000.0f;
        float c1 = (p0 + 1 < NS) ? -0.5f * w1 : -60000.0f;
        float c2 = (p0 + 2 < NS) ? -0.5f * w2 : -60000.0f;
        float c3 = (p0 + 3 < NS) ? -0.5f * w3 : -60000.0f;
        const int qq = p0 & 31;
        const int W = ((p0 >> 5) << 4) + (((qq & 15) >> 2) << 2) + ((qq >> 4) << 1);
        uint2 hw = { pkh_rne(c0, c1), pkh_rne(c2, c3) };
        *reinterpret_cast<uint2*>(&nwh[W]) = hw;
    }

    __builtin_amdgcn_wave_barrier();   // order pass-2 stores before main-loop reads

    // --- main loop: 16 bodies x 2 tile-pairs; ALL loads+cvts at body top
    //     (one lgkmcnt point per 2 iters; 16 back-to-back MFMAs follow).
    //     Straight-line SSA: no conditionals, no rotation (r6/r8 spill-safe). ---
    float rmax[4][4];
    #pragma unroll
    for (int lt = 0; lt < 4; ++lt)
        #pragma unroll
        for (int e = 0; e < 4; ++e) rmax[lt][e] = -3.0e38f;

    const int par = col & 1;
    const uint32_t* apk = (par ? pkO : pkE) + (((col - par) >> 1) + kg * 4);
    const int nwb = 4 * kg;

    #pragma unroll 1
    for (int p = 0; p < 16; ++p) {
        const uint32_t* ap0 = apk + 32 * p;
        const uint32_t* ap1 = apk + 32 * p + 16;

        // -- all 6 LDS reads --
        fragh Aa0, Ab0, Aa1, Ab1;
        #pragma unroll
        for (int j = 0; j < 4; ++j) Aa0.u[j] = ap0[j];
        #pragma unroll
        for (int j = 0; j < 4; ++j) Ab0.u[j] = ap0[8 + j];
        #pragma unroll
        for (int j = 0; j < 4; ++j) Aa1.u[j] = ap1[j];
        #pragma unroll
        for (int j = 0; j < 4; ++j) Ab1.u[j] = ap1[8 + j];
        uint4 nw0 = *reinterpret_cast<const uint4*>(&nwh[32 * p + nwb]);
        uint4 nw1 = *reinterpret_cast<const uint4*>(&nwh[32 * p + 16 + nwb]);

        // -- all 16 cvts --
        f32x4 ia0, ib0, ia1, ib1;
        ia0[0] = lo16f(nw0.x); ia0[1] = hi16f(nw0.x);
        ia0[2] = lo16f(nw0.y); ia0[3] = hi16f(nw0.y);
        ib0[0] = lo16f(nw0.z); ib0[1] = hi16f(nw0.z);
        ib0[2] = lo16f(nw0.w); ib0[3] = hi16f(nw0.w);
        ia1[0] = lo16f(nw1.x); ia1[1] = hi16f(nw1.x);
        ia1[2] = lo16f(nw1.y); ia1[3] = hi16f(nw1.y);
        ib1[0] = lo16f(nw1.z); ib1[1] = hi16f(nw1.z);
        ib1[2] = lo16f(nw1.w); ib1[3] = hi16f(nw1.w);

        // -- 16 MFMAs + 32 max3 --
        #pragma unroll
        for (int lt = 0; lt < 4; ++lt) {
            f32x4 aa0 = __builtin_amdgcn_mfma_f32_16x16x32_f16(Aa0.v, Bh[lt].v, ia0, 0, 0, 0);
            f32x4 ab0 = __builtin_amdgcn_mfma_f32_16x16x32_f16(Ab0.v, Bh[lt].v, ib0, 0, 0, 0);
            f32x4 aa1 = __builtin_amdgcn_mfma_f32_16x16x32_f16(Aa1.v, Bh[lt].v, ia1, 0, 0, 0);
            f32x4 ab1 = __builtin_amdgcn_mfma_f32_16x16x32_f16(Ab1.v, Bh[lt].v, ib1, 0, 0, 0);
            #pragma unroll
            for (int e = 0; e < 4; ++e) {
                rmax[lt][e] = fmaxf(fmaxf(aa0[e], ab0[e]), rmax[lt][e]);  // v_max3_f32
                rmax[lt][e] = fmaxf(fmaxf(aa1[e], ab1[e]), rmax[lt][e]);  // v_max3_f32
            }
        }
    }

    // --- epilogue: all in-wave shuffles, no LDS, no barrier ---
    float p0v = 0.0f, p1v = 0.0f;
    #pragma unroll
    for (int lt = 0; lt < 4; ++lt) {
        float m = fmaxf(fmaxf(rmax[lt][0], rmax[lt][1]),
                        fmaxf(rmax[lt][2], rmax[lt][3]));
        m = fmaxf(m, __shfl_xor(m, 16, 64));
        m = fmaxf(m, __shfl_xor(m, 32, 64));
        float sq = ssq[lt];
        sq += __shfl_xor(sq, 16, 64);
        sq += __shfl_xor(sq, 32, 64);
        float f = (sq - 2.0f * m) * (1.0f / (float)KLEN);   // min dist
        p0v = fmaf(f, fc_w[lt * 16 + col], p0v);
        p1v = fmaf(f, fc_w[NL + lt * 16 + col], p1v);
    }
    #pragma unroll
    for (int off = 1; off <= 8; off <<= 1) {
        p0v += __shfl_xor(p0v, off, 64);
        p1v += __shfl_xor(p1v, off, 64);
    }
    if (lane == 0) {
        out[(size_t)row * 2 + 0] = p0v + fc_b[0];
        out[(size_t)row * 2 + 1] = p1v + fc_b[1];
    }
}

extern "C" void kernel_launch(void* const* d_in, const int* in_sizes, int n_in,
                              void* d_out, int out_size, void* d_ws, size_t ws_size,
                              hipStream_t stream) {
    const float* ts        = (const float*)d_in[0];
    const float* shapelets = (const float*)d_in[1];
    const float* fc_w      = (const float*)d_in[2];
    const float* fc_b      = (const float*)d_in[3];
    float* out = (float*)d_out;

    shapelet_r15<<<NB / 4, 256, 0, stream>>>(ts, shapelets, fc_w, fc_b, out);
}